// Round 7
// baseline (639.227 us; speedup 1.0000x reference)
//
#include <hip/hip_runtime.h>
#include <hip/hip_bf16.h>

#define NN 15135
#define BS 8
#define FIN 64
#define HD 128
#define EE 242160
#define HFC 512
#define NCLS 10

#define M_ROWS (BS * NN)          // 121080
#define PADE   287616             // >= EE + 3*NN (CSR rows padded to multiple of 4)
#define NT     237                // node tiles of 64: 237*64 = 15168 >= NN
#define CAP    2048               // CSR pairs staged per chunk (16 KB)

#define NCH 237                   // fc1 chunks of 64 rows
#define NPLANES (NCH * 2)

typedef __attribute__((ext_vector_type(8))) short bf16x8;
typedef __attribute__((ext_vector_type(4))) float f32x4;

__device__ __forceinline__ unsigned short to_bf16(float f) {
    unsigned u = __float_as_uint(f);
    u = (u + 0x7fffu + ((u >> 16) & 1u)) >> 16;       // RNE
    return (unsigned short)u;
}
__device__ __forceinline__ unsigned pack2_bf16(float lo, float hi) {
    unsigned a = __float_as_uint(lo);
    unsigned b = __float_as_uint(hi);
    a = (a + 0x7fffu + ((a >> 16) & 1u)) >> 16;
    b = (b + 0x7fffu + ((b >> 16) & 1u)) & 0xffff0000u;
    return (a & 0xffffu) | b;
}

// ---------------- degree histogram ----------------
__global__ void k_deg(const int* __restrict__ dst, int* __restrict__ degi) {
    int e = blockIdx.x * 256 + threadIdx.x;
    if (e < EE) atomicAdd(&degi[dst[e]], 1);
}

// ---------------- scan (padded-to-4 degrees) + dinv ----------------
#define SCAN_T 1024
#define SCAN_PER 15
__global__ __launch_bounds__(SCAN_T) void k_scan(const int* __restrict__ degi,
                                                 int* __restrict__ row_ptr,
                                                 float* __restrict__ dinv) {
    __shared__ int part[SCAN_T];
    const int t = threadIdx.x;
    const int base = t * SCAN_PER;
    int loc[SCAN_PER];
    int s = 0;
#pragma unroll
    for (int i = 0; i < SCAN_PER; i++) {
        int d = (base + i < NN) ? degi[base + i] : 0;
        if (base + i < NN) dinv[base + i] = rsqrtf((float)d + 1.0f);
        int pd = (d + 3) & ~3;
        loc[i] = s; s += pd;
    }
    part[t] = s;
    __syncthreads();
    for (int off = 1; off < SCAN_T; off <<= 1) {
        int v = (t >= off) ? part[t - off] : 0;
        __syncthreads();
        part[t] += v;
        __syncthreads();
    }
    int before = (t == 0) ? 0 : part[t - 1];
#pragma unroll
    for (int i = 0; i < SCAN_PER; i++)
        if (base + i < NN) row_ptr[base + i] = before + loc[i];
    if (t == SCAN_T - 1) row_ptr[NN] = part[SCAN_T - 1];
}

// ---------------- bucket fill: interleaved (s, w) pairs ----------------
__global__ void k_bucket(const int* __restrict__ src, const int* __restrict__ dst,
                         const int* __restrict__ row_ptr, int* __restrict__ cursor,
                         const float* __restrict__ dinv, int2* __restrict__ csr) {
    int e = blockIdx.x * 256 + threadIdx.x;
    if (e >= EE) return;
    int s = src[e], d = dst[e];
    int pos = atomicAdd(&cursor[d], 1);
    csr[row_ptr[d] + pos] = make_int2(s, __float_as_int(dinv[s] * dinv[d]));
}

// ---------------- all 3 W [K,128] fp32 -> Wt [128,K] bf16 ----------------
__global__ void k_cvtW(const float* __restrict__ W1, const float* __restrict__ W2,
                       const float* __restrict__ W3, unsigned short* __restrict__ Wt) {
    int idx = blockIdx.x * 256 + threadIdx.x;     // 0..40959
    const float* W; int K, base;
    if (idx < 8192)       { W = W1; K = 64;  base = idx; }
    else if (idx < 24576) { W = W2; K = 128; base = idx - 8192; }
    else                  { W = W3; K = 128; base = idx - 24576; }
    int c = base / K, k = base % K;
    Wt[idx] = to_bf16(W[(size_t)k * HD + c]);
}

// ============ fused conv1: gather fp32 x + MFMA(K=64) + epilogue ============
__global__ __launch_bounds__(256) void k_conv1(const float* __restrict__ x,
                                               const int2* __restrict__ csr,
                                               const int* __restrict__ rp,
                                               const float* __restrict__ dinv,
                                               const unsigned short* __restrict__ Wt,
                                               const float* __restrict__ bias,
                                               const float* __restrict__ Wfc,
                                               const float* __restrict__ bfc,
                                               unsigned short* __restrict__ H,
                                               float* __restrict__ g) {
    __shared__ int4 smem[CAP / 2];        // 16 KB: CSR chunk, later A-tile (8 KB)
    __shared__ float gred[4][64];
    const int tid = threadIdx.x;
    const int widx = tid >> 6, lane = tid & 63;
    const int bb = blockIdx.y;
    const int t0 = blockIdx.x * 64;
    const float* Xbase = x + (size_t)bb * NN * FIN;

    // row_ptr for my wave's 16 nodes via one load + readlane
    int rpi = t0 + widx * 16 + (lane <= 16 ? lane : 16);
    int rpv = rp[rpi < NN ? rpi : NN];
    int e0[16], e1[16];
    float ax[16];
#pragma unroll
    for (int i = 0; i < 16; i++) {
        e0[i] = __shfl(rpv, i, 64);
        e1[i] = __shfl(rpv, i + 1, 64);
        int n = t0 + widx * 16 + i;
        if (n < NN) {
            float dv = dinv[n];
            ax[i] = dv * dv * Xbase[(size_t)n * FIN + lane];
        } else ax[i] = 0.f;
    }
    const int blockBase = __builtin_amdgcn_readfirstlane(rp[t0]);
    const int tEnd = (t0 + 64 < NN) ? t0 + 64 : NN;
    const int blockEnd = __builtin_amdgcn_readfirstlane(rp[tEnd]);

    for (int cb = blockBase; cb < blockEnd; cb += CAP) {
        const int ce = (cb + CAP < blockEnd) ? cb + CAP : blockEnd;
        const int np4 = (ce - cb) >> 1;
        const int4* gsrc = (const int4*)(csr + cb);
        for (int j = tid; j < np4; j += 256) smem[j] = gsrc[j];
        __syncthreads();
#pragma unroll
        for (int i = 0; i < 16; i++) {
            int a = e0[i] > cb ? e0[i] : cb;
            int b = e1[i] < ce ? e1[i] : ce;
            for (int e = a; e < b; e += 4) {
                int4 m0 = smem[(e - cb) >> 1];
                int4 m1 = smem[((e - cb) >> 1) + 1];
                float u0 = Xbase[(size_t)m0.x * FIN + lane];
                float u1 = Xbase[(size_t)m0.z * FIN + lane];
                float u2 = Xbase[(size_t)m1.x * FIN + lane];
                float u3 = Xbase[(size_t)m1.z * FIN + lane];
                ax[i] += __int_as_float(m0.y) * u0;
                ax[i] += __int_as_float(m0.w) * u1;
                ax[i] += __int_as_float(m1.y) * u2;
                ax[i] += __int_as_float(m1.w) * u3;
            }
        }
        __syncthreads();
    }
    // write swizzled A-tile [64][64] bf16 into smem
    unsigned short* As = (unsigned short*)smem;
#pragma unroll
    for (int i = 0; i < 16; i++) {
        int r = widx * 16 + i;
        int byte = (r * 128 + lane * 2) ^ ((r & 7) << 4);
        *(unsigned short*)((char*)As + byte) = to_bf16(ax[i]);
    }
    __syncthreads();

    // MFMA phase: K=64
    const int l15 = lane & 15, lhi = lane >> 4;
    const int cbase = widx * 32;
    bf16x8 B[2][2];
#pragma unroll
    for (int ct = 0; ct < 2; ct++)
#pragma unroll
        for (int ks = 0; ks < 2; ks++)
            B[ct][ks] = *(const bf16x8*)&Wt[(size_t)(cbase + ct * 16 + l15) * 64 + ks * 32 + lhi * 8];
    f32x4 acc[4][2] = {};
#pragma unroll
    for (int ks = 0; ks < 2; ks++) {
        bf16x8 A[4];
#pragma unroll
        for (int rt = 0; rt < 4; rt++) {
            int r = rt * 16 + l15;
            int byte = (r * 128 + ks * 64 + lhi * 16) ^ ((r & 7) << 4);
            A[rt] = *(const bf16x8*)((const char*)As + byte);
        }
#pragma unroll
        for (int rt = 0; rt < 4; rt++)
#pragma unroll
            for (int ct = 0; ct < 2; ct++)
                acc[rt][ct] = __builtin_amdgcn_mfma_f32_16x16x32_bf16(A[rt], B[ct][ks], acc[rt][ct], 0, 0, 0);
    }

    const float bias0 = bias[cbase + l15], bias1 = bias[cbase + 16 + l15];
    const float wf0 = Wfc[(cbase + l15) * 3 + 0];
    const float wf1 = Wfc[(cbase + 16 + l15) * 3 + 0];
#pragma unroll
    for (int rt = 0; rt < 4; rt++) {
#pragma unroll
        for (int reg = 0; reg < 4; reg++) {
            const int lr = rt * 16 + lhi * 4 + reg;
            const int n = t0 + lr;
            float h0 = fmaxf(acc[rt][0][reg] + bias0, 0.f);
            float h1 = fmaxf(acc[rt][1][reg] + bias1, 0.f);
            if (n < NN) {
                H[((size_t)bb * NN + n) * HD + cbase + l15] = to_bf16(h0);
                H[((size_t)bb * NN + n) * HD + cbase + 16 + l15] = to_bf16(h1);
            }
            float p = h0 * wf0 + h1 * wf1;
#pragma unroll
            for (int m = 8; m; m >>= 1) p += __shfl_xor(p, m, 64);
            if (l15 == 0) gred[widx][lr] = p;
        }
    }
    __syncthreads();
    if (tid < 64) {
        const int n = t0 + tid;
        if (n < NN) g[bb * NN + n] = bfc[0] + gred[0][tid] + gred[1][tid] + gred[2][tid] + gred[3][tid];
    }
}

// ============ fused conv2/3: gather bf16 + MFMA(K=128) + epilogue ============
template<int LIDX, bool STOREH>
__global__ __launch_bounds__(256) void k_conv23(const unsigned short* __restrict__ Xb,
                                                const int2* __restrict__ csr,
                                                const int* __restrict__ rp,
                                                const float* __restrict__ dinv,
                                                const unsigned short* __restrict__ Wt,
                                                const float* __restrict__ bias,
                                                const float* __restrict__ Wfc,
                                                unsigned short* __restrict__ H,
                                                float* __restrict__ g) {
    __shared__ int4 smem[CAP / 2];        // 16 KB: CSR chunk, later A-tile (16 KB)
    __shared__ float gred[4][64];
    const int tid = threadIdx.x;
    const int widx = tid >> 6, lane = tid & 63;
    const int bb = blockIdx.y;
    const int t0 = blockIdx.x * 64;
    const unsigned short* Xbase = Xb + (size_t)bb * NN * HD;

    int rpi = t0 + widx * 16 + (lane <= 16 ? lane : 16);
    int rpv = rp[rpi < NN ? rpi : NN];
    int e0[16], e1[16];
    float ax[16], ay[16];
#pragma unroll
    for (int i = 0; i < 16; i++) {
        e0[i] = __shfl(rpv, i, 64);
        e1[i] = __shfl(rpv, i + 1, 64);
        int n = t0 + widx * 16 + i;
        if (n < NN) {
            float dv = dinv[n];
            float w0 = dv * dv;
            unsigned u = *(const unsigned*)&Xbase[(size_t)n * HD + lane * 2];
            ax[i] = w0 * __uint_as_float(u << 16);
            ay[i] = w0 * __uint_as_float(u & 0xffff0000u);
        } else { ax[i] = 0.f; ay[i] = 0.f; }
    }
    const int blockBase = __builtin_amdgcn_readfirstlane(rp[t0]);
    const int tEnd = (t0 + 64 < NN) ? t0 + 64 : NN;
    const int blockEnd = __builtin_amdgcn_readfirstlane(rp[tEnd]);

    for (int cb = blockBase; cb < blockEnd; cb += CAP) {
        const int ce = (cb + CAP < blockEnd) ? cb + CAP : blockEnd;
        const int np4 = (ce - cb) >> 1;
        const int4* gsrc = (const int4*)(csr + cb);
        for (int j = tid; j < np4; j += 256) smem[j] = gsrc[j];
        __syncthreads();
#pragma unroll
        for (int i = 0; i < 16; i++) {
            int a = e0[i] > cb ? e0[i] : cb;
            int b = e1[i] < ce ? e1[i] : ce;
            for (int e = a; e < b; e += 4) {
                int4 m0 = smem[(e - cb) >> 1];
                int4 m1 = smem[((e - cb) >> 1) + 1];
                unsigned u0 = *(const unsigned*)&Xbase[(size_t)m0.x * HD + lane * 2];
                unsigned u1 = *(const unsigned*)&Xbase[(size_t)m0.z * HD + lane * 2];
                unsigned u2 = *(const unsigned*)&Xbase[(size_t)m1.x * HD + lane * 2];
                unsigned u3 = *(const unsigned*)&Xbase[(size_t)m1.z * HD + lane * 2];
                float w0 = __int_as_float(m0.y), w1 = __int_as_float(m0.w);
                float w2 = __int_as_float(m1.y), w3 = __int_as_float(m1.w);
                ax[i] += w0 * __uint_as_float(u0 << 16); ay[i] += w0 * __uint_as_float(u0 & 0xffff0000u);
                ax[i] += w1 * __uint_as_float(u1 << 16); ay[i] += w1 * __uint_as_float(u1 & 0xffff0000u);
                ax[i] += w2 * __uint_as_float(u2 << 16); ay[i] += w2 * __uint_as_float(u2 & 0xffff0000u);
                ax[i] += w3 * __uint_as_float(u3 << 16); ay[i] += w3 * __uint_as_float(u3 & 0xffff0000u);
            }
        }
        __syncthreads();
    }
    unsigned short* As = (unsigned short*)smem;
#pragma unroll
    for (int i = 0; i < 16; i++) {
        int r = widx * 16 + i;
        int byte = (r * 256 + lane * 4) ^ ((r & 7) << 4);
        *(unsigned*)((char*)As + byte) = pack2_bf16(ax[i], ay[i]);
    }
    __syncthreads();

    // MFMA phase: K=128
    const int l15 = lane & 15, lhi = lane >> 4;
    const int cbase = widx * 32;
    bf16x8 B[2][4];
#pragma unroll
    for (int ct = 0; ct < 2; ct++)
#pragma unroll
        for (int ks = 0; ks < 4; ks++)
            B[ct][ks] = *(const bf16x8*)&Wt[(size_t)(cbase + ct * 16 + l15) * HD + ks * 32 + lhi * 8];
    f32x4 acc[4][2] = {};
#pragma unroll
    for (int ks = 0; ks < 4; ks++) {
        bf16x8 A[4];
#pragma unroll
        for (int rt = 0; rt < 4; rt++) {
            int r = rt * 16 + l15;
            int byte = (r * 256 + ks * 64 + lhi * 16) ^ ((r & 7) << 4);
            A[rt] = *(const bf16x8*)((const char*)As + byte);
        }
#pragma unroll
        for (int rt = 0; rt < 4; rt++)
#pragma unroll
            for (int ct = 0; ct < 2; ct++)
                acc[rt][ct] = __builtin_amdgcn_mfma_f32_16x16x32_bf16(A[rt], B[ct][ks], acc[rt][ct], 0, 0, 0);
    }

    const float bias0 = bias[cbase + l15], bias1 = bias[cbase + 16 + l15];
    const float wf0 = Wfc[(cbase + l15) * 3 + LIDX];
    const float wf1 = Wfc[(cbase + 16 + l15) * 3 + LIDX];
#pragma unroll
    for (int rt = 0; rt < 4; rt++) {
#pragma unroll
        for (int reg = 0; reg < 4; reg++) {
            const int lr = rt * 16 + lhi * 4 + reg;
            const int n = t0 + lr;
            float h0 = fmaxf(acc[rt][0][reg] + bias0, 0.f);
            float h1 = fmaxf(acc[rt][1][reg] + bias1, 0.f);
            if (STOREH && n < NN) {
                H[((size_t)bb * NN + n) * HD + cbase + l15] = to_bf16(h0);
                H[((size_t)bb * NN + n) * HD + cbase + 16 + l15] = to_bf16(h1);
            }
            float p = h0 * wf0 + h1 * wf1;
#pragma unroll
            for (int m = 8; m; m >>= 1) p += __shfl_xor(p, m, 64);
            if (l15 == 0) gred[widx][lr] = p;
        }
    }
    __syncthreads();
    if (tid < 64) {
        const int n = t0 + tid;
        if (n < NN) g[bb * NN + n] += gred[0][tid] + gred[1][tid] + gred[2][tid] + gred[3][tid];
    }
}

// ---------------- fc1 partials ----------------
__global__ __launch_bounds__(256) void k_fc1part(const float* __restrict__ g,
                                                 const float* __restrict__ Wl1,
                                                 float* __restrict__ part) {
    const int ct = threadIdx.x & 127;
    const int st = threadIdx.x >> 7;
    const int n0 = blockIdx.x * 64;
    __shared__ float gs[BS][64];
    for (int i = threadIdx.x; i < BS * 64; i += 256) {
        int b = i >> 6, j = i & 63;
        int n = n0 + j;
        gs[b][j] = (n < NN) ? g[b * NN + n] : 0.f;
    }
    __syncthreads();

    f32x4 acc[BS] = {};
    const int jend = (64 < NN - n0) ? 64 : NN - n0;
#pragma unroll 4
    for (int j = st; j < jend; j += 2) {
        f32x4 wv = *(const f32x4*)&Wl1[(size_t)(n0 + j) * HFC + 4 * ct];
#pragma unroll
        for (int b = 0; b < BS; b++) acc[b] += gs[b][j] * wv;
    }
    float* p = &part[((size_t)(blockIdx.x * 2 + st)) * (BS * HFC)];
#pragma unroll
    for (int b = 0; b < BS; b++)
        *(f32x4*)&p[b * HFC + 4 * ct] = acc[b];
}

__global__ __launch_bounds__(128) void k_fc1red(const float* __restrict__ part,
                                                const float* __restrict__ bl1,
                                                float* __restrict__ z) {
    const int idx = blockIdx.x * 128 + threadIdx.x;
    float s = 0.f;
#pragma unroll 8
    for (int y = 0; y < NPLANES; y++) s += part[(size_t)y * (BS * HFC) + idx];
    z[idx] = fmaxf(s + bl1[idx & 511], 0.f);
}

__global__ void k_head(const float* __restrict__ z, const float* __restrict__ Wl2,
                       const float* __restrict__ bl2, float* __restrict__ out) {
    __shared__ float lg[BS][NCLS];
    const int t = threadIdx.x;
    if (t < BS * NCLS) {
        int b = t / NCLS, c = t % NCLS;
        float a = bl2[c];
        for (int k = 0; k < HFC; k++) a += z[b * HFC + k] * Wl2[k * NCLS + c];
        lg[b][c] = a;
    }
    __syncthreads();
    if (t < BS * NCLS) {
        int b = t / NCLS, c = t % NCLS;
        float m = -1e30f;
#pragma unroll
        for (int j = 0; j < NCLS; j++) m = fmaxf(m, lg[b][j]);
        float s = 0.f;
#pragma unroll
        for (int j = 0; j < NCLS; j++) s += expf(lg[b][j] - m);
        out[b * NCLS + c] = lg[b][c] - m - logf(s);
    }
}

extern "C" void kernel_launch(void* const* d_in, const int* in_sizes, int n_in,
                              void* d_out, int out_size, void* d_ws, size_t ws_size,
                              hipStream_t stream) {
    const float* x   = (const float*)d_in[0];
    const int*   ei  = (const int*)d_in[1];
    const float* W1  = (const float*)d_in[2];
    const float* b1  = (const float*)d_in[3];
    const float* W2  = (const float*)d_in[4];
    const float* b2  = (const float*)d_in[5];
    const float* W3  = (const float*)d_in[6];
    const float* b3  = (const float*)d_in[7];
    const float* Wfc = (const float*)d_in[8];
    const float* bfc = (const float*)d_in[9];
    const float* Wl1 = (const float*)d_in[10];
    const float* bl1 = (const float*)d_in[11];
    const float* Wl2 = (const float*)d_in[12];
    const float* bl2 = (const float*)d_in[13];
    float* out = (float*)d_out;

    const int* srcp = ei;
    const int* dstp = ei + EE;

    float* ws = (float*)d_ws;
    float* dinv    = ws;                               // 15360
    float* g       = ws + 15360;                       // 121088
    float* z       = ws + 136448;                      // 4096
    float* part    = ws + 140544;                      // 474*4096 = 1941504
    int*   degi    = (int*)(ws + 2082048);             // 15360
    int*   cursor  = (int*)(ws + 2097408);             // 15360 (contiguous w/ degi)
    int*   row_ptr = (int*)(ws + 2112768);             // 15488
    int2*  csr     = (int2*)(ws + 2128256);            // PADE pairs (8 B each)
    unsigned short* Wt  = (unsigned short*)(ws + 2703488);  // 40960 us
    unsigned short* Wt1 = Wt;
    unsigned short* Wt2 = Wt + 8192;
    unsigned short* Wt3 = Wt + 24576;
    unsigned short* B1  = (unsigned short*)(ws + 2723968);  // [BS][NN][128] bf16
    unsigned short* B2  = (unsigned short*)(ws + 10473600); // [BS][NN][128] bf16

    hipMemsetAsync(degi, 0, 2 * 15360 * sizeof(int), stream);        // degi + cursor
    hipMemsetAsync(csr, 0, (size_t)PADE * 8, stream);                // (s=0, w=0) pads
    k_deg<<<(EE + 255) / 256, 256, 0, stream>>>(dstp, degi);
    k_scan<<<1, SCAN_T, 0, stream>>>(degi, row_ptr, dinv);
    k_bucket<<<(EE + 255) / 256, 256, 0, stream>>>(srcp, dstp, row_ptr, cursor, dinv, csr);
    k_cvtW<<<160, 256, 0, stream>>>(W1, W2, W3, Wt);

    k_conv1<<<dim3(NT, 8), 256, 0, stream>>>(x, csr, row_ptr, dinv, Wt1, b1, Wfc, bfc, B1, g);
    k_conv23<1, true><<<dim3(NT, 8), 256, 0, stream>>>(B1, csr, row_ptr, dinv, Wt2, b2, Wfc, B2, g);
    k_conv23<2, false><<<dim3(NT, 8), 256, 0, stream>>>(B2, csr, row_ptr, dinv, Wt3, b3, Wfc, nullptr, g);

    k_fc1part<<<NCH, 256, 0, stream>>>(g, Wl1, part);
    k_fc1red<<<32, 128, 0, stream>>>(part, bl1, z);
    k_head<<<1, 128, 0, stream>>>(z, Wl2, bl2, out);
}

// Round 8
// 457.352 us; speedup vs baseline: 1.3977x; 1.3977x over previous
//
#include <hip/hip_runtime.h>
#include <hip/hip_bf16.h>

#define NN 15135
#define BS 8
#define FIN 64
#define HD 128
#define EE 242160
#define HFC 512
#define NCLS 10

#define M_ROWS (BS * NN)          // 121080
#define M_PAD  121088             // 64 * 1892
#define PADE   348160             // >= EE + 7*NN (CSR rows padded to multiple of 8)
#define NT4    3784               // node tiles of 4: 3784*4 = 15136 >= NN

#define NCH 237                   // fc1 chunks of 64 rows
#define NPLANES (NCH * 2)

typedef __attribute__((ext_vector_type(8))) short bf16x8;
typedef __attribute__((ext_vector_type(4))) float f32x4;

__device__ __forceinline__ unsigned short to_bf16(float f) {
    unsigned u = __float_as_uint(f);
    u = (u + 0x7fffu + ((u >> 16) & 1u)) >> 16;       // RNE
    return (unsigned short)u;
}
__device__ __forceinline__ unsigned pack2_bf16(float lo, float hi) {
    unsigned a = __float_as_uint(lo);
    unsigned b = __float_as_uint(hi);
    a = (a + 0x7fffu + ((a >> 16) & 1u)) >> 16;
    b = (b + 0x7fffu + ((b >> 16) & 1u)) & 0xffff0000u;
    return (a & 0xffffu) | b;
}

// ---------------- degree histogram ----------------
__global__ void k_deg(const int* __restrict__ dst, int* __restrict__ degi) {
    int e = blockIdx.x * 256 + threadIdx.x;
    if (e < EE) atomicAdd(&degi[dst[e]], 1);
}

// ---------------- scan (padded-to-8 degrees) + dinv ----------------
#define SCAN_T 1024
#define SCAN_PER 15
__global__ __launch_bounds__(SCAN_T) void k_scan(const int* __restrict__ degi,
                                                 int* __restrict__ row_ptr,
                                                 float* __restrict__ dinv) {
    __shared__ int part[SCAN_T];
    const int t = threadIdx.x;
    const int base = t * SCAN_PER;
    int loc[SCAN_PER];
    int s = 0;
#pragma unroll
    for (int i = 0; i < SCAN_PER; i++) {
        int d = (base + i < NN) ? degi[base + i] : 0;
        if (base + i < NN) dinv[base + i] = rsqrtf((float)d + 1.0f);
        int pd = (d + 7) & ~7;          // pad row to multiple of 8
        loc[i] = s; s += pd;
    }
    part[t] = s;
    __syncthreads();
    for (int off = 1; off < SCAN_T; off <<= 1) {
        int v = (t >= off) ? part[t - off] : 0;
        __syncthreads();
        part[t] += v;
        __syncthreads();
    }
    int before = (t == 0) ? 0 : part[t - 1];
#pragma unroll
    for (int i = 0; i < SCAN_PER; i++)
        if (base + i < NN) row_ptr[base + i] = before + loc[i];
    if (t == SCAN_T - 1) row_ptr[NN] = part[SCAN_T - 1];
}

// ---------------- bucket fill (padded slots stay s=0,w=0 from memset) --------
__global__ void k_bucket(const int* __restrict__ src, const int* __restrict__ dst,
                         const int* __restrict__ row_ptr, int* __restrict__ cursor,
                         const float* __restrict__ dinv,
                         int* __restrict__ s_idx, float* __restrict__ wts) {
    int e = blockIdx.x * 256 + threadIdx.x;
    if (e >= EE) return;
    int s = src[e], d = dst[e];
    int pos = atomicAdd(&cursor[d], 1);
    int idx = row_ptr[d] + pos;
    s_idx[idx] = s;
    wts[idx] = dinv[s] * dinv[d];
}

// ---------------- all 3 W [K,128] fp32 -> Wt [128,K] bf16 ----------------
__global__ void k_cvtW(const float* __restrict__ W1, const float* __restrict__ W2,
                       const float* __restrict__ W3, unsigned short* __restrict__ Wt) {
    int idx = blockIdx.x * 256 + threadIdx.x;     // 0..40959
    const float* W; int K, base;
    if (idx < 8192)       { W = W1; K = 64;  base = idx; }
    else if (idx < 24576) { W = W2; K = 128; base = idx - 8192; }
    else                  { W = W3; K = 128; base = idx - 24576; }
    int c = base / K, k = base % K;
    Wt[idx] = to_bf16(W[(size_t)k * HD + c]);
}

// ---------------- conv1 aggregate: fp32 x gather, XCD-affine batch ----------
// 1D grid NT4*8: bb = bid&7 (== XCD), 4 waves = 4 nodes; lane = feat (64)
__global__ __launch_bounds__(256) void k_aggx(const float* __restrict__ x,
                                              const int* __restrict__ rp,
                                              const int* __restrict__ s_idx,
                                              const float* __restrict__ wts,
                                              const float* __restrict__ dinv,
                                              unsigned short* __restrict__ Ab) {
    const int tid = threadIdx.x;
    const int widx = tid >> 6, lane = tid & 63;
    const int bid = blockIdx.x;
    const int bb = bid & 7;
    const int n = (bid >> 3) * 4 + widx;
    if (n >= NN) return;
    const float* Xs = x + (size_t)bb * NN * FIN;

    const int e0 = __builtin_amdgcn_readfirstlane(rp[n]);
    const int e1 = __builtin_amdgcn_readfirstlane(rp[n + 1]);
    const float dv = dinv[n];
    float acc0 = dv * dv * Xs[(size_t)n * FIN + lane];
    float acc1 = 0.f;

    for (int c = e0; c < e1; c += 8) {
        int s0 = s_idx[c + 0], s1 = s_idx[c + 1], s2 = s_idx[c + 2], s3 = s_idx[c + 3];
        int s4 = s_idx[c + 4], s5 = s_idx[c + 5], s6 = s_idx[c + 6], s7 = s_idx[c + 7];
        float w0 = wts[c + 0], w1 = wts[c + 1], w2 = wts[c + 2], w3 = wts[c + 3];
        float w4 = wts[c + 4], w5 = wts[c + 5], w6 = wts[c + 6], w7 = wts[c + 7];
        float u0 = Xs[(size_t)s0 * FIN + lane];
        float u1 = Xs[(size_t)s1 * FIN + lane];
        float u2 = Xs[(size_t)s2 * FIN + lane];
        float u3 = Xs[(size_t)s3 * FIN + lane];
        float u4 = Xs[(size_t)s4 * FIN + lane];
        float u5 = Xs[(size_t)s5 * FIN + lane];
        float u6 = Xs[(size_t)s6 * FIN + lane];
        float u7 = Xs[(size_t)s7 * FIN + lane];
        acc0 += w0 * u0; acc1 += w1 * u1;
        acc0 += w2 * u2; acc1 += w3 * u3;
        acc0 += w4 * u4; acc1 += w5 * u5;
        acc0 += w6 * u6; acc1 += w7 * u7;
    }
    Ab[(size_t)bb * NN * FIN + (size_t)n * FIN + lane] = to_bf16(acc0 + acc1);
}

// ---------------- conv2/3 aggregate: bf16 gather, XCD-affine batch ----------
// 1D grid NT4*8: bb = bid&7, 4 waves = 4 nodes; lane = feat-pair (128)
__global__ __launch_bounds__(256) void k_agg128(const unsigned short* __restrict__ Xb,
                                                const int* __restrict__ rp,
                                                const int* __restrict__ s_idx,
                                                const float* __restrict__ wts,
                                                const float* __restrict__ dinv,
                                                unsigned short* __restrict__ Ab) {
    const int tid = threadIdx.x;
    const int widx = tid >> 6, lane = tid & 63;
    const int bid = blockIdx.x;
    const int bb = bid & 7;
    const int n = (bid >> 3) * 4 + widx;
    if (n >= NN) return;
    const unsigned short* Xs = Xb + (size_t)bb * NN * HD + 2 * lane;

    const int e0 = __builtin_amdgcn_readfirstlane(rp[n]);
    const int e1 = __builtin_amdgcn_readfirstlane(rp[n + 1]);
    const float dv = dinv[n];

    float ax0, ay0, ax1 = 0.f, ay1 = 0.f;
    {
        unsigned u = *(const unsigned*)&Xs[(size_t)n * HD];
        float w0 = dv * dv;
        ax0 = w0 * __uint_as_float(u << 16);
        ay0 = w0 * __uint_as_float(u & 0xffff0000u);
    }
    for (int c = e0; c < e1; c += 8) {
        int s0 = s_idx[c + 0], s1 = s_idx[c + 1], s2 = s_idx[c + 2], s3 = s_idx[c + 3];
        int s4 = s_idx[c + 4], s5 = s_idx[c + 5], s6 = s_idx[c + 6], s7 = s_idx[c + 7];
        float w0 = wts[c + 0], w1 = wts[c + 1], w2 = wts[c + 2], w3 = wts[c + 3];
        float w4 = wts[c + 4], w5 = wts[c + 5], w6 = wts[c + 6], w7 = wts[c + 7];
        unsigned u0 = *(const unsigned*)&Xs[(size_t)s0 * HD];
        unsigned u1 = *(const unsigned*)&Xs[(size_t)s1 * HD];
        unsigned u2 = *(const unsigned*)&Xs[(size_t)s2 * HD];
        unsigned u3 = *(const unsigned*)&Xs[(size_t)s3 * HD];
        unsigned u4 = *(const unsigned*)&Xs[(size_t)s4 * HD];
        unsigned u5 = *(const unsigned*)&Xs[(size_t)s5 * HD];
        unsigned u6 = *(const unsigned*)&Xs[(size_t)s6 * HD];
        unsigned u7 = *(const unsigned*)&Xs[(size_t)s7 * HD];
        ax0 += w0 * __uint_as_float(u0 << 16); ay0 += w0 * __uint_as_float(u0 & 0xffff0000u);
        ax1 += w1 * __uint_as_float(u1 << 16); ay1 += w1 * __uint_as_float(u1 & 0xffff0000u);
        ax0 += w2 * __uint_as_float(u2 << 16); ay0 += w2 * __uint_as_float(u2 & 0xffff0000u);
        ax1 += w3 * __uint_as_float(u3 << 16); ay1 += w3 * __uint_as_float(u3 & 0xffff0000u);
        ax0 += w4 * __uint_as_float(u4 << 16); ay0 += w4 * __uint_as_float(u4 & 0xffff0000u);
        ax1 += w5 * __uint_as_float(u5 << 16); ay1 += w5 * __uint_as_float(u5 & 0xffff0000u);
        ax0 += w6 * __uint_as_float(u6 << 16); ay0 += w6 * __uint_as_float(u6 & 0xffff0000u);
        ax1 += w7 * __uint_as_float(u7 << 16); ay1 += w7 * __uint_as_float(u7 & 0xffff0000u);
    }
    *(unsigned*)&Ab[(size_t)bb * NN * HD + (size_t)n * HD + 2 * lane] =
        pack2_bf16(ax0 + ax1, ay0 + ay1);
}

// ---------------- MFMA GEMM + fused epilogue ----------------
template<int KD, int LIDX, bool GINIT, bool STOREH>
__global__ __launch_bounds__(256) void k_gemm_ep(const unsigned short* __restrict__ Xb,
                                                 const unsigned short* __restrict__ Wt,
                                                 const float* __restrict__ bias,
                                                 const float* __restrict__ Wfc,
                                                 const float* __restrict__ bfc,
                                                 unsigned short* __restrict__ H,
                                                 float* __restrict__ g) {
    constexpr int NK = KD / 32;
    const int tid = threadIdx.x;
    const int w = tid >> 6, lane = tid & 63;
    const int l15 = lane & 15, lhi = lane >> 4;
    const int row0 = blockIdx.x * 64;
    const int cbase = w * 32;

    bf16x8 B[2][NK];
#pragma unroll
    for (int ct = 0; ct < 2; ct++)
#pragma unroll
        for (int ks = 0; ks < NK; ks++)
            B[ct][ks] = *(const bf16x8*)&Wt[(size_t)(cbase + ct * 16 + l15) * KD + ks * 32 + lhi * 8];

    f32x4 acc[4][2] = {};
#pragma unroll
    for (int ks = 0; ks < NK; ks++) {
        bf16x8 A[4];
#pragma unroll
        for (int rt = 0; rt < 4; rt++)
            A[rt] = *(const bf16x8*)&Xb[(size_t)(row0 + rt * 16 + l15) * KD + ks * 32 + lhi * 8];
#pragma unroll
        for (int rt = 0; rt < 4; rt++)
#pragma unroll
            for (int ct = 0; ct < 2; ct++)
                acc[rt][ct] = __builtin_amdgcn_mfma_f32_16x16x32_bf16(A[rt], B[ct][ks], acc[rt][ct], 0, 0, 0);
    }

    __shared__ float gred[4][64];
    const float bias0 = bias[cbase + l15], bias1 = bias[cbase + 16 + l15];
    const float wf0 = Wfc[(cbase + l15) * 3 + LIDX];
    const float wf1 = Wfc[(cbase + 16 + l15) * 3 + LIDX];
#pragma unroll
    for (int rt = 0; rt < 4; rt++) {
#pragma unroll
        for (int reg = 0; reg < 4; reg++) {
            const int row = row0 + rt * 16 + lhi * 4 + reg;
            float h0 = fmaxf(acc[rt][0][reg] + bias0, 0.f);
            float h1 = fmaxf(acc[rt][1][reg] + bias1, 0.f);
            if (STOREH) {
                H[(size_t)row * 128 + cbase + l15] = to_bf16(h0);
                H[(size_t)row * 128 + cbase + 16 + l15] = to_bf16(h1);
            }
            float p = h0 * wf0 + h1 * wf1;
#pragma unroll
            for (int m = 8; m; m >>= 1) p += __shfl_xor(p, m, 64);
            if (l15 == 0) gred[w][rt * 16 + lhi * 4 + reg] = p;
        }
    }
    __syncthreads();
    if (tid < 64) {
        const int row = row0 + tid;
        if (row < M_ROWS) {
            float s = gred[0][tid] + gred[1][tid] + gred[2][tid] + gred[3][tid];
            if (GINIT) g[row] = bfc[0] + s; else g[row] += s;
        }
    }
}

// ---------------- fc1 partials ----------------
__global__ __launch_bounds__(256) void k_fc1part(const float* __restrict__ g,
                                                 const float* __restrict__ Wl1,
                                                 float* __restrict__ part) {
    const int ct = threadIdx.x & 127;
    const int st = threadIdx.x >> 7;
    const int n0 = blockIdx.x * 64;
    __shared__ float gs[BS][64];
    for (int i = threadIdx.x; i < BS * 64; i += 256) {
        int b = i >> 6, j = i & 63;
        int n = n0 + j;
        gs[b][j] = (n < NN) ? g[b * NN + n] : 0.f;
    }
    __syncthreads();

    f32x4 acc[BS] = {};
    const int jend = (64 < NN - n0) ? 64 : NN - n0;
#pragma unroll 4
    for (int j = st; j < jend; j += 2) {
        f32x4 wv = *(const f32x4*)&Wl1[(size_t)(n0 + j) * HFC + 4 * ct];
#pragma unroll
        for (int b = 0; b < BS; b++) acc[b] += gs[b][j] * wv;
    }
    float* p = &part[((size_t)(blockIdx.x * 2 + st)) * (BS * HFC)];
#pragma unroll
    for (int b = 0; b < BS; b++)
        *(f32x4*)&p[b * HFC + 4 * ct] = acc[b];
}

__global__ __launch_bounds__(128) void k_fc1red(const float* __restrict__ part,
                                                const float* __restrict__ bl1,
                                                float* __restrict__ z) {
    const int idx = blockIdx.x * 128 + threadIdx.x;
    float s = 0.f;
#pragma unroll 8
    for (int y = 0; y < NPLANES; y++) s += part[(size_t)y * (BS * HFC) + idx];
    z[idx] = fmaxf(s + bl1[idx & 511], 0.f);
}

__global__ void k_head(const float* __restrict__ z, const float* __restrict__ Wl2,
                       const float* __restrict__ bl2, float* __restrict__ out) {
    __shared__ float lg[BS][NCLS];
    const int t = threadIdx.x;
    if (t < BS * NCLS) {
        int b = t / NCLS, c = t % NCLS;
        float a = bl2[c];
        for (int k = 0; k < HFC; k++) a += z[b * HFC + k] * Wl2[k * NCLS + c];
        lg[b][c] = a;
    }
    __syncthreads();
    if (t < BS * NCLS) {
        int b = t / NCLS, c = t % NCLS;
        float m = -1e30f;
#pragma unroll
        for (int j = 0; j < NCLS; j++) m = fmaxf(m, lg[b][j]);
        float s = 0.f;
#pragma unroll
        for (int j = 0; j < NCLS; j++) s += expf(lg[b][j] - m);
        out[b * NCLS + c] = lg[b][c] - m - logf(s);
    }
}

extern "C" void kernel_launch(void* const* d_in, const int* in_sizes, int n_in,
                              void* d_out, int out_size, void* d_ws, size_t ws_size,
                              hipStream_t stream) {
    const float* x   = (const float*)d_in[0];
    const int*   ei  = (const int*)d_in[1];
    const float* W1  = (const float*)d_in[2];
    const float* b1  = (const float*)d_in[3];
    const float* W2  = (const float*)d_in[4];
    const float* b2  = (const float*)d_in[5];
    const float* W3  = (const float*)d_in[6];
    const float* b3  = (const float*)d_in[7];
    const float* Wfc = (const float*)d_in[8];
    const float* bfc = (const float*)d_in[9];
    const float* Wl1 = (const float*)d_in[10];
    const float* bl1 = (const float*)d_in[11];
    const float* Wl2 = (const float*)d_in[12];
    const float* bl2 = (const float*)d_in[13];
    float* out = (float*)d_out;

    const int* srcp = ei;
    const int* dstp = ei + EE;

    float* ws = (float*)d_ws;
    float* dinv    = ws;                               // 15360
    float* g       = ws + 15360;                       // 121088
    float* z       = ws + 136448;                      // 4096
    float* part    = ws + 140544;                      // 1941504
    int*   degi    = (int*)(ws + 2082048);             // 15360
    int*   cursor  = (int*)(ws + 2097408);             // 15360 (contiguous w/ degi)
    int*   row_ptr = (int*)(ws + 2112768);             // 15488
    int*   s_idx   = (int*)(ws + 2128256);             // PADE
    float* wts     = ws + 2476416;                     // PADE (contiguous w/ s_idx)
    unsigned short* Wt  = (unsigned short*)(ws + 2824576);  // 40960 us
    unsigned short* Wt1 = Wt;
    unsigned short* Wt2 = Wt + 8192;
    unsigned short* Wt3 = Wt + 24576;
    unsigned short* a0  = (unsigned short*)(ws + 2845056);  // [BS][NN][64] bf16
    unsigned short* B1  = (unsigned short*)(ws + 6719872);  // [BS][NN][128] bf16
    unsigned short* B2  = (unsigned short*)(ws + 14469504); // [BS][NN][128] bf16

    const int gemm_grid = M_PAD / 64;                  // 1892

    hipMemsetAsync(degi, 0, 2 * 15360 * sizeof(int), stream);        // degi + cursor
    hipMemsetAsync(s_idx, 0, 2 * PADE * sizeof(int), stream);        // s_idx + wts
    k_deg<<<(EE + 255) / 256, 256, 0, stream>>>(dstp, degi);
    k_scan<<<1, SCAN_T, 0, stream>>>(degi, row_ptr, dinv);
    k_bucket<<<(EE + 255) / 256, 256, 0, stream>>>(srcp, dstp, row_ptr, cursor, dinv, s_idx, wts);
    k_cvtW<<<160, 256, 0, stream>>>(W1, W2, W3, Wt);

    // conv1: a0 = agg(x)[fp32->bf16, 64-wide]; h1(B1) = relu(a0@W1+b1), g = bfc + h1.Wfc0
    k_aggx<<<NT4 * 8, 256, 0, stream>>>(x, row_ptr, s_idx, wts, dinv, a0);
    k_gemm_ep<64, 0, true, true><<<gemm_grid, 256, 0, stream>>>(a0, Wt1, b1, Wfc, bfc, B1, g);
    // conv2: a1(B2) = agg(h1); h2(B1) = relu(a1@W2+b2), g += h2.Wfc1
    k_agg128<<<NT4 * 8, 256, 0, stream>>>(B1, row_ptr, s_idx, wts, dinv, B2);
    k_gemm_ep<128, 1, false, true><<<gemm_grid, 256, 0, stream>>>(B2, Wt2, b2, Wfc, bfc, B1, g);
    // conv3: a2(B2) = agg(h2); g += h3.Wfc2 (h3 not stored)
    k_agg128<<<NT4 * 8, 256, 0, stream>>>(B1, row_ptr, s_idx, wts, dinv, B2);
    k_gemm_ep<128, 2, false, false><<<gemm_grid, 256, 0, stream>>>(B2, Wt3, b3, Wfc, bfc, B1, g);

    k_fc1part<<<NCH, 256, 0, stream>>>(g, Wl1, part);
    k_fc1red<<<32, 128, 0, stream>>>(part, bl1, z);
    k_head<<<1, 128, 0, stream>>>(z, Wl2, bl2, out);
}